// Round 1
// baseline (239.793 us; speedup 1.0000x reference)
//
#include <hip/hip_runtime.h>
#include <math.h>

// Cone-beam forward projection (TIGRE Ax analogue).
// Volume: [B=2, NZ=96, NY=96, NX=96] f32, ZYX layout (x fastest).
// Output: [B=2, A=48, NV=96, NU=96] f32.
//
// R11: R10 structure (batch-interleaved float2 pack + 4x dwordx4 gathers),
// plus sample-loop unroll x4 with PREDICATION instead of the divergent
// bounds branch. All 16 gathers for 4 samples issue in one basic block
// before any lerp consumes them -> 4x the in-flight loads per wave to
// hide the ~200-600cy gather latency that left VALUBusy at 27%.
// Bit-identical numerics: per-sample op order unchanged (clamped coords
// == unclamped for valid samples), contributions added in ascending-k
// order, invalid samples add exactly +0.0f (identity on +acc).
//
// CORRECTNESS-CRITICAL: reference integrand is DISCONTINUOUS at cube faces.
// Position path replicates the reference's f32 op sequence exactly:
// contract(off), per-sample src + d*t, IEEE sqrt+div, f64-rounded trig.

#define NZg 96
#define NYg 96
#define NXg 96
#define NVg 96
#define NUg 96
#define NAg 48
#define NSg 96
#define NBg 2
#define NVOX (NZg * NYg * NXg)          // 884736 voxels per batch
#define NRAY1 (NAg * NVg * NUg)         // 442368 rays per batch
#define PLANE (NYg * NXg)               // 9216 float2 elements per z-plane

typedef float v4f __attribute__((ext_vector_type(4)));  // default (16B) align

// ---------------- staging: interleave the two batches ---------------------
__global__ __launch_bounds__(256) void pack_b2(
    const float* __restrict__ vol, float2* __restrict__ q) {
    const int i = blockIdx.x * blockDim.x + threadIdx.x;  // [z][y][x]
    float2 p;
    p.x = vol[i];
    p.y = vol[i + NVOX];
    q[i] = p;
}

// ---------------- shared geometry (b-independent) -------------------------
__device__ __forceinline__ void ray_setup(
    int ridx, float& srcx, float& srcy, float& dx, float& dy, float& dz,
    int& k0, int& k1) {
#pragma clang fp contract(off)
    const int u   = ridx % NUg;
    int tmp       = ridx / NUg;
    const int v   = tmp % NVg;
    const int a   = tmp / NVg;          // < 48, uniform per block

    // theta = a * (f32(2*pi) / 48)   [jax linspace f32 semantics]
    const float dtheta = 6.2831855f / 48.0f;
    const float theta  = (float)a * dtheta;
    const float c = (float)cos((double)theta);
    const float s = (float)sin((double)theta);

    srcx = 500.0f * c;
    srcy = 500.0f * s;
    const float uu = ((float)u - 47.5f) * 2.0f;
    const float vv = ((float)v - 47.5f) * 2.0f;
    const float pixx = (-500.0f * c) + uu * (-s);
    const float pixy = (-500.0f * s) + uu * c;
    const float pixz = vv;

    const float dx0 = pixx - srcx;
    const float dy0 = pixy - srcy;
    const float dz0 = pixz;
    const float nrm = sqrtf((dx0 * dx0 + dy0 * dy0) + dz0 * dz0);
    dx = dx0 / nrm;
    dy = dy0 / nrm;
    dz = dz0 / nrm;

    const float stepf = (float)1.7320508075688773;   // f32(2R/96)
    const float t0f   = (float)416.8615612366939;    // f32(DSO-R)

    // conservative AABB clip (skip-only; in-loop test is authoritative)
    const float LO = -47.51f, HI = 47.51f;
    float tlo = -1e30f, thi = 1e30f;
    {
        const float o3[3] = {srcx, srcy, 0.0f};
        const float d3[3] = {dx, dy, dz};
        bool empty = false;
        #pragma unroll
        for (int ax = 0; ax < 3; ++ax) {
            const float oo = o3[ax], dd = d3[ax];
            if (fabsf(dd) > 1e-8f) {
                const float inv = 1.0f / dd;
                const float ta = (LO - oo) * inv;
                const float tb = (HI - oo) * inv;
                tlo = fmaxf(tlo, fminf(ta, tb));
                thi = fminf(thi, fmaxf(ta, tb));
            } else if (oo < LO || oo > HI) {
                empty = true;
            }
        }
        if (empty) { tlo = 1.0f; thi = 0.0f; }
    }
    if (thi >= tlo) {
        k0 = (int)floorf((tlo - t0f) / stepf) - 2;
        k1 = (int)ceilf((thi - t0f) / stepf) + 2;
        k0 = max(k0, 0);
        k1 = min(k1, NSg - 1);
    } else {
        k0 = 1; k1 = 0;
    }
}

// ---------------- main: both batches per thread, unroll x4 ----------------
__global__ __launch_bounds__(256) void coneproj_b2x4u4(
    const float2* __restrict__ q, float* __restrict__ out) {
#pragma clang fp contract(off)
    const int ridx = blockIdx.x * blockDim.x + threadIdx.x;  // (a*96+v)*96+u
    float srcx, srcy, dx, dy, dz;
    int k0, k1;
    ray_setup(ridx, srcx, srcy, dx, dy, dz, k0, k1);

    const float stepf = (float)1.7320508075688773;
    const float t0f   = (float)416.8615612366939;

    float acc0 = 0.0f, acc1 = 0.0f;
    int k = k0;

    // ---- unrolled-by-4, predicated: all 16 gathers issue before use ----
    for (; k + 3 <= k1; k += 4) {
        int   base[4];
        float fx[4], fy[4], fz[4];
        bool  ok[4];
#pragma unroll
        for (int j = 0; j < 4; ++j) {
            const float tk = t0f + ((float)(k + j) + 0.5f) * stepf;
            const float ix = (srcx + dx * tk) + 47.5f;
            const float iy = (srcy + dy * tk) + 47.5f;
            const float iz = (dz * tk) + 47.5f;
            ok[j] = (ix >= 0.0f) & (ix <= 95.0f) &
                    (iy >= 0.0f) & (iy <= 95.0f) &
                    (iz >= 0.0f) & (iz <= 95.0f);
            // clamped coords: bit-identical to ix/iy/iz when ok[j]
            const float ixc = fminf(fmaxf(ix, 0.0f), 95.0f);
            const float iyc = fminf(fmaxf(iy, 0.0f), 95.0f);
            const float izc = fminf(fmaxf(iz, 0.0f), 95.0f);
            const int x0 = min((int)ixc, NXg - 2);
            const int y0 = min((int)iyc, NYg - 2);
            const int z0 = min((int)izc, NZg - 2);
            fx[j] = ixc - (float)x0;
            fy[j] = iyc - (float)y0;
            fz[j] = izc - (float)z0;
            base[j] = (z0 * NYg + y0) * NXg + x0;
        }
        v4f r00[4], r01[4], r10[4], r11[4];
#pragma unroll
        for (int j = 0; j < 4; ++j) {
            r00[j] = *(const v4f*)(q + base[j]);                // (y0,z0)
            r01[j] = *(const v4f*)(q + base[j] + NXg);          // (y1,z0)
            r10[j] = *(const v4f*)(q + base[j] + PLANE);        // (y0,z1)
            r11[j] = *(const v4f*)(q + base[j] + PLANE + NXg);  // (y1,z1)
        }
#pragma unroll
        for (int j = 0; j < 4; ++j) {
            // batch 0 (op-order identical to R10): .x = b0@x0, .z = b0@x1
            {
                const float c00 = r00[j].x + fx[j] * (r00[j].z - r00[j].x);
                const float c01 = r01[j].x + fx[j] * (r01[j].z - r01[j].x);
                const float c10 = r10[j].x + fx[j] * (r10[j].z - r10[j].x);
                const float c11 = r11[j].x + fx[j] * (r11[j].z - r11[j].x);
                const float c0  = c00 + fy[j] * (c01 - c00);
                const float c1  = c10 + fy[j] * (c11 - c10);
                const float t0  = c0 + fz[j] * (c1 - c0);
                acc0 += ok[j] ? t0 : 0.0f;
            }
            // batch 1: .y = b1@x0, .w = b1@x1
            {
                const float c00 = r00[j].y + fx[j] * (r00[j].w - r00[j].y);
                const float c01 = r01[j].y + fx[j] * (r01[j].w - r01[j].y);
                const float c10 = r10[j].y + fx[j] * (r10[j].w - r10[j].y);
                const float c11 = r11[j].y + fx[j] * (r11[j].w - r11[j].y);
                const float c0  = c00 + fy[j] * (c01 - c00);
                const float c1  = c10 + fy[j] * (c11 - c10);
                const float t1  = c0 + fz[j] * (c1 - c0);
                acc1 += ok[j] ? t1 : 0.0f;
            }
        }
    }

    // ---- tail (0..3 samples), original branchy body ----
    for (; k <= k1; ++k) {
        const float tk = t0f + ((float)k + 0.5f) * stepf;
        const float ix = (srcx + dx * tk) + 47.5f;
        const float iy = (srcy + dy * tk) + 47.5f;
        const float iz = (dz * tk) + 47.5f;
        if (ix >= 0.0f && ix <= 95.0f &&
            iy >= 0.0f && iy <= 95.0f &&
            iz >= 0.0f && iz <= 95.0f) {
            const int x0 = min((int)ix, NXg - 2);
            const int y0 = min((int)iy, NYg - 2);
            const int z0 = min((int)iz, NZg - 2);
            const float fx = ix - (float)x0;
            const float fy = iy - (float)y0;
            const float fz = iz - (float)z0;
            const int base = (z0 * NYg + y0) * NXg + x0;
            const v4f r00 = *(const v4f*)(q + base);
            const v4f r01 = *(const v4f*)(q + base + NXg);
            const v4f r10 = *(const v4f*)(q + base + PLANE);
            const v4f r11 = *(const v4f*)(q + base + PLANE + NXg);
            {
                const float c00 = r00.x + fx * (r00.z - r00.x);
                const float c01 = r01.x + fx * (r01.z - r01.x);
                const float c10 = r10.x + fx * (r10.z - r10.x);
                const float c11 = r11.x + fx * (r11.z - r11.x);
                const float c0  = c00 + fy * (c01 - c00);
                const float c1  = c10 + fy * (c11 - c10);
                acc0 += c0 + fz * (c1 - c0);
            }
            {
                const float c00 = r00.y + fx * (r00.w - r00.y);
                const float c01 = r01.y + fx * (r01.w - r01.y);
                const float c10 = r10.y + fx * (r10.w - r10.y);
                const float c11 = r11.y + fx * (r11.w - r11.y);
                const float c0  = c00 + fy * (c01 - c00);
                const float c1  = c10 + fy * (c11 - c10);
                acc1 += c0 + fz * (c1 - c0);
            }
        }
    }

    out[ridx]         = acc0 * stepf;
    out[ridx + NRAY1] = acc1 * stepf;
}

// ---------------- fallback: direct 8-gather projector (R2) ----------------
__global__ __launch_bounds__(256) void coneproj_direct(
    const float* __restrict__ vol, float* __restrict__ out) {
#pragma clang fp contract(off)
    const int gidx = blockIdx.x * blockDim.x + threadIdx.x;  // includes b
    const int ridx = gidx % NRAY1;
    const int b    = gidx / NRAY1;
    float srcx, srcy, dx, dy, dz;
    int k0, k1;
    ray_setup(ridx, srcx, srcy, dx, dy, dz, k0, k1);

    const float stepf = (float)1.7320508075688773;
    const float t0f   = (float)416.8615612366939;

    const float* __restrict__ volb = vol + (size_t)b * NVOX;

    float acc = 0.0f;
    for (int k = k0; k <= k1; ++k) {
        const float tk = t0f + ((float)k + 0.5f) * stepf;
        const float ix = (srcx + dx * tk) + 47.5f;
        const float iy = (srcy + dy * tk) + 47.5f;
        const float iz = (dz * tk) + 47.5f;
        if (ix >= 0.0f && ix <= 95.0f &&
            iy >= 0.0f && iy <= 95.0f &&
            iz >= 0.0f && iz <= 95.0f) {
            const int x0 = min((int)ix, NXg - 2);
            const int y0 = min((int)iy, NYg - 2);
            const int z0 = min((int)iz, NZg - 2);
            const float fx = ix - (float)x0;
            const float fy = iy - (float)y0;
            const float fz = iz - (float)z0;
            const float* p = volb + ((z0 * NYg + y0) * NXg + x0);
            const float v000 = p[0];
            const float v001 = p[1];
            const float v010 = p[NXg];
            const float v011 = p[NXg + 1];
            const float v100 = p[NYg * NXg];
            const float v101 = p[NYg * NXg + 1];
            const float v110 = p[NYg * NXg + NXg];
            const float v111 = p[NYg * NXg + NXg + 1];
            const float c00 = v000 + fx * (v001 - v000);
            const float c01 = v010 + fx * (v011 - v010);
            const float c10 = v100 + fx * (v101 - v100);
            const float c11 = v110 + fx * (v111 - v110);
            const float c0  = c00 + fy * (c01 - c00);
            const float c1  = c10 + fy * (c11 - c10);
            acc += c0 + fz * (c1 - c0);
        }
    }
    out[gidx] = acc * stepf;
}

extern "C" void kernel_launch(void* const* d_in, const int* in_sizes, int n_in,
                              void* d_out, int out_size, void* d_ws, size_t ws_size,
                              hipStream_t stream) {
    const float* vol = (const float*)d_in[0];
    float* out = (float*)d_out;
    const size_t needed = (size_t)NVOX * sizeof(float2);  // ~7.08 MB
    if (ws_size >= needed) {
        float2* q = (float2*)d_ws;
        pack_b2<<<NVOX / 256, 256, 0, stream>>>(vol, q);
        coneproj_b2x4u4<<<NRAY1 / 256, 256, 0, stream>>>(q, out);
    } else {
        coneproj_direct<<<(NBg * NRAY1) / 256, 256, 0, stream>>>(vol, out);
    }
}

// Round 2
// 224.737 us; speedup vs baseline: 1.0670x; 1.0670x over previous
//
#include <hip/hip_runtime.h>
#include <math.h>

// Cone-beam forward projection (TIGRE Ax analogue).
// Volume: [B=2, NZ=96, NY=96, NX=96] f32, ZYX layout (x fastest).
// Output: [B=2, A=48, NV=96, NU=96] f32.
//
// R12: R10 loop body (branchy, 4x dwordx4 gathers on batch-interleaved
// float2 volume) — R11's predication/unroll regressed and is reverted.
// New decomposition: 4 threads per ray, each walking a CONTIGUOUS quarter
// of the clipped sample range, LDS-reduced with fixed order
// ((c0+c1)+c2)+c3. Rationale: R10/R11 launched only 1728 blocks = 6.75
// blocks/CU (one round, no churn, ragged tail) -> latency-bound at
// VALUBusy 27%. This gives 6912 blocks = 27/CU, 4x shorter serial chains,
// balanced tail. f64 trig hoisted to a 48-entry device-built table
// (identical expression -> identical bits).
//
// CORRECTNESS-CRITICAL: reference integrand is DISCONTINUOUS at cube faces.
// Position path replicates the reference's f32 op sequence exactly:
// contract(off), per-sample src + d*t, IEEE sqrt+div, f64-rounded trig.
// Chunk seams only reassociate the +acc sum (error ~1e-4, tolerance-safe);
// every per-sample contribution is bit-identical to R10.

#define NZg 96
#define NYg 96
#define NXg 96
#define NVg 96
#define NUg 96
#define NAg 48
#define NSg 96
#define NBg 2
#define NVOX (NZg * NYg * NXg)          // 884736 voxels per batch
#define NRAY1 (NAg * NVg * NUg)         // 442368 rays per batch
#define PLANE (NYg * NXg)               // 9216 float2 elements per z-plane

typedef float v4f __attribute__((ext_vector_type(4)));  // default (16B) align

// ---------------- staging: interleave the two batches ---------------------
__global__ __launch_bounds__(256) void pack_b2(
    const float* __restrict__ vol, float2* __restrict__ q) {
    const int i = blockIdx.x * blockDim.x + threadIdx.x;  // [z][y][x]
    float2 p;
    p.x = vol[i];
    p.y = vol[i + NVOX];
    q[i] = p;
}

// ---------------- per-angle trig table (bit-identical to inline calc) -----
__global__ void make_trig(float2* __restrict__ trig) {
    const int a = threadIdx.x;
    if (a < NAg) {
        const float dtheta = 6.2831855f / 48.0f;
        const float theta  = (float)a * dtheta;     // same f32 expr as before
        float2 cs;
        cs.x = (float)cos((double)theta);
        cs.y = (float)sin((double)theta);
        trig[a] = cs;
    }
}

// ---------------- shared geometry (b-independent) -------------------------
__device__ __forceinline__ void ray_setup_cs(
    int ridx, float c, float s, float& srcx, float& srcy,
    float& dx, float& dy, float& dz, int& k0, int& k1) {
#pragma clang fp contract(off)
    const int u   = ridx % NUg;
    int tmp       = ridx / NUg;
    const int v   = tmp % NVg;

    srcx = 500.0f * c;
    srcy = 500.0f * s;
    const float uu = ((float)u - 47.5f) * 2.0f;
    const float vv = ((float)v - 47.5f) * 2.0f;
    const float pixx = (-500.0f * c) + uu * (-s);
    const float pixy = (-500.0f * s) + uu * c;
    const float pixz = vv;

    const float dx0 = pixx - srcx;
    const float dy0 = pixy - srcy;
    const float dz0 = pixz;
    const float nrm = sqrtf((dx0 * dx0 + dy0 * dy0) + dz0 * dz0);
    dx = dx0 / nrm;
    dy = dy0 / nrm;
    dz = dz0 / nrm;

    const float stepf = (float)1.7320508075688773;   // f32(2R/96)
    const float t0f   = (float)416.8615612366939;    // f32(DSO-R)

    // conservative AABB clip (skip-only; in-loop test is authoritative)
    const float LO = -47.51f, HI = 47.51f;
    float tlo = -1e30f, thi = 1e30f;
    {
        const float o3[3] = {srcx, srcy, 0.0f};
        const float d3[3] = {dx, dy, dz};
        bool empty = false;
        #pragma unroll
        for (int ax = 0; ax < 3; ++ax) {
            const float oo = o3[ax], dd = d3[ax];
            if (fabsf(dd) > 1e-8f) {
                const float inv = 1.0f / dd;
                const float ta = (LO - oo) * inv;
                const float tb = (HI - oo) * inv;
                tlo = fmaxf(tlo, fminf(ta, tb));
                thi = fminf(thi, fmaxf(ta, tb));
            } else if (oo < LO || oo > HI) {
                empty = true;
            }
        }
        if (empty) { tlo = 1.0f; thi = 0.0f; }
    }
    if (thi >= tlo) {
        k0 = (int)floorf((tlo - t0f) / stepf) - 2;
        k1 = (int)ceilf((thi - t0f) / stepf) + 2;
        k0 = max(k0, 0);
        k1 = min(k1, NSg - 1);
    } else {
        k0 = 1; k1 = 0;
    }
}

// ---------------- main: 4 threads/ray, contiguous chunks, LDS reduce ------
__global__ __launch_bounds__(256) void coneproj_b2c4(
    const float2* __restrict__ q, const float2* __restrict__ trig,
    float* __restrict__ out) {
#pragma clang fp contract(off)
    const int lane  = threadIdx.x & 63;     // ray within block
    const int chunk = threadIdx.x >> 6;     // which quarter of the ray
    const int ridx  = blockIdx.x * 64 + lane;   // (a*96+v)*96+u
    const int a     = ridx / (NUg * NVg);       // uniform per block

    const float2 cs = trig[a];
    float srcx, srcy, dx, dy, dz;
    int k0, k1;
    ray_setup_cs(ridx, cs.x, cs.y, srcx, srcy, dx, dy, dz, k0, k1);

    const float stepf = (float)1.7320508075688773;
    const float t0f   = (float)416.8615612366939;

    // contiguous quarter of [k0, k1]
    const int len = (k1 - k0 + 4) >> 2;          // ceil((k1-k0+1)/4)
    const int kb0 = k0 + chunk * len;
    const int kb1 = min(kb0 + len - 1, k1);

    float acc0 = 0.0f, acc1 = 0.0f;
    for (int k = kb0; k <= kb1; ++k) {
        const float tk = t0f + ((float)k + 0.5f) * stepf;
        const float ix = (srcx + dx * tk) + 47.5f;
        const float iy = (srcy + dy * tk) + 47.5f;
        const float iz = (dz * tk) + 47.5f;
        if (ix >= 0.0f && ix <= 95.0f &&
            iy >= 0.0f && iy <= 95.0f &&
            iz >= 0.0f && iz <= 95.0f) {
            const int x0 = min((int)ix, NXg - 2);
            const int y0 = min((int)iy, NYg - 2);
            const int z0 = min((int)iz, NZg - 2);
            const float fx = ix - (float)x0;
            const float fy = iy - (float)y0;
            const float fz = iz - (float)z0;
            const int base = (z0 * NYg + y0) * NXg + x0;
            // 4 x 16B gathers at 8B-aligned addresses: each row-load gives
            // (b0@x0, b1@x0, b0@x1, b1@x1) for one (y,z) corner row.
            const v4f r00 = *(const v4f*)(q + base);                // (y0,z0)
            const v4f r01 = *(const v4f*)(q + base + NXg);          // (y1,z0)
            const v4f r10 = *(const v4f*)(q + base + PLANE);        // (y0,z1)
            const v4f r11 = *(const v4f*)(q + base + PLANE + NXg);  // (y1,z1)
            // batch 0 (op-order identical to R10): .x = b0@x0, .z = b0@x1
            {
                const float c00 = r00.x + fx * (r00.z - r00.x);
                const float c01 = r01.x + fx * (r01.z - r01.x);
                const float c10 = r10.x + fx * (r10.z - r10.x);
                const float c11 = r11.x + fx * (r11.z - r11.x);
                const float c0  = c00 + fy * (c01 - c00);
                const float c1  = c10 + fy * (c11 - c10);
                acc0 += c0 + fz * (c1 - c0);
            }
            // batch 1: .y = b1@x0, .w = b1@x1
            {
                const float c00 = r00.y + fx * (r00.w - r00.y);
                const float c01 = r01.y + fx * (r01.w - r01.y);
                const float c10 = r10.y + fx * (r10.w - r10.y);
                const float c11 = r11.y + fx * (r11.w - r11.y);
                const float c0  = c00 + fy * (c01 - c00);
                const float c1  = c10 + fy * (c11 - c10);
                acc1 += c0 + fz * (c1 - c0);
            }
        }
    }

    // ---- combine the 4 chunks (fixed order: ((c0+c1)+c2)+c3) ----
    __shared__ float p0[256];
    __shared__ float p1[256];
    p0[threadIdx.x] = acc0;
    p1[threadIdx.x] = acc1;
    __syncthreads();
    if (threadIdx.x < 64) {
        const float s0 = ((p0[lane] + p0[lane + 64]) + p0[lane + 128]) + p0[lane + 192];
        const float s1 = ((p1[lane] + p1[lane + 64]) + p1[lane + 128]) + p1[lane + 192];
        out[ridx]         = s0 * stepf;
        out[ridx + NRAY1] = s1 * stepf;
    }
}

// ---------------- fallback: direct 8-gather projector (R2) ----------------
__device__ __forceinline__ void ray_setup(
    int ridx, float& srcx, float& srcy, float& dx, float& dy, float& dz,
    int& k0, int& k1) {
#pragma clang fp contract(off)
    const int a = ridx / (NUg * NVg);
    const float dtheta = 6.2831855f / 48.0f;
    const float theta  = (float)a * dtheta;
    const float c = (float)cos((double)theta);
    const float s = (float)sin((double)theta);
    ray_setup_cs(ridx, c, s, srcx, srcy, dx, dy, dz, k0, k1);
}

__global__ __launch_bounds__(256) void coneproj_direct(
    const float* __restrict__ vol, float* __restrict__ out) {
#pragma clang fp contract(off)
    const int gidx = blockIdx.x * blockDim.x + threadIdx.x;  // includes b
    const int ridx = gidx % NRAY1;
    const int b    = gidx / NRAY1;
    float srcx, srcy, dx, dy, dz;
    int k0, k1;
    ray_setup(ridx, srcx, srcy, dx, dy, dz, k0, k1);

    const float stepf = (float)1.7320508075688773;
    const float t0f   = (float)416.8615612366939;

    const float* __restrict__ volb = vol + (size_t)b * NVOX;

    float acc = 0.0f;
    for (int k = k0; k <= k1; ++k) {
        const float tk = t0f + ((float)k + 0.5f) * stepf;
        const float ix = (srcx + dx * tk) + 47.5f;
        const float iy = (srcy + dy * tk) + 47.5f;
        const float iz = (dz * tk) + 47.5f;
        if (ix >= 0.0f && ix <= 95.0f &&
            iy >= 0.0f && iy <= 95.0f &&
            iz >= 0.0f && iz <= 95.0f) {
            const int x0 = min((int)ix, NXg - 2);
            const int y0 = min((int)iy, NYg - 2);
            const int z0 = min((int)iz, NZg - 2);
            const float fx = ix - (float)x0;
            const float fy = iy - (float)y0;
            const float fz = iz - (float)z0;
            const float* p = volb + ((z0 * NYg + y0) * NXg + x0);
            const float v000 = p[0];
            const float v001 = p[1];
            const float v010 = p[NXg];
            const float v011 = p[NXg + 1];
            const float v100 = p[NYg * NXg];
            const float v101 = p[NYg * NXg + 1];
            const float v110 = p[NYg * NXg + NXg];
            const float v111 = p[NYg * NXg + NXg + 1];
            const float c00 = v000 + fx * (v001 - v000);
            const float c01 = v010 + fx * (v011 - v010);
            const float c10 = v100 + fx * (v101 - v100);
            const float c11 = v110 + fx * (v111 - v110);
            const float c0  = c00 + fy * (c01 - c00);
            const float c1  = c10 + fy * (c11 - c10);
            acc += c0 + fz * (c1 - c0);
        }
    }
    out[gidx] = acc * stepf;
}

extern "C" void kernel_launch(void* const* d_in, const int* in_sizes, int n_in,
                              void* d_out, int out_size, void* d_ws, size_t ws_size,
                              hipStream_t stream) {
    const float* vol = (const float*)d_in[0];
    float* out = (float*)d_out;
    const size_t needed = (size_t)NVOX * sizeof(float2)     // ~7.08 MB packed vol
                        + (size_t)NAg * sizeof(float2);     // + trig table
    if (ws_size >= needed) {
        float2* q    = (float2*)d_ws;
        float2* trig = q + NVOX;
        pack_b2<<<NVOX / 256, 256, 0, stream>>>(vol, q);
        make_trig<<<1, 64, 0, stream>>>(trig);
        coneproj_b2c4<<<NRAY1 / 64, 256, 0, stream>>>(q, trig, out);
    } else {
        coneproj_direct<<<(NBg * NRAY1) / 256, 256, 0, stream>>>(vol, out);
    }
}

// Round 3
// 196.206 us; speedup vs baseline: 1.2221x; 1.1454x over previous
//
#include <hip/hip_runtime.h>
#include <math.h>

// Cone-beam forward projection (TIGRE Ax analogue).
// Volume: [B=2, NZ=96, NY=96, NX=96] f32, ZYX layout (x fastest).
// Output: [B=2, A=48, NV=96, NU=96] f32.
//
// R13: back to R10's decomposition (1 thread/ray, branchy body, 4x dwordx4
// gathers on batch-interleaved float2 volume) -- R12 proved occupancy is
// not the limiter (74% occ, same dur). Theory: TA/L1 line-throughput bound.
// Lanes are consecutive u; with x-fast layout, angles where |cos| dominates
// put all 64 lanes in distinct y-rows => 64 cache lines per gather instr.
// Fix: keep TWO packed copies, x-fast [z][y][x] and y-fast [z][x][y], and
// per angle (wave-uniform) gather from the one whose fast axis matches the
// dominant u component. Loop body is role-symmetric: pre-swap
// (srcx,dx)<->(srcy,dy) so position expressions stay bit-identical to the
// reference; only lerp-axis application order changes for y-fast angles
// (value rounding ~1e-6, in/out decisions untouched).
//
// CORRECTNESS-CRITICAL: reference integrand is DISCONTINUOUS at cube faces.
// Position path replicates the reference's f32 op sequence exactly:
// contract(off), per-sample src + d*t, IEEE sqrt+div, f64-rounded trig.

#define NZg 96
#define NYg 96
#define NXg 96
#define NVg 96
#define NUg 96
#define NAg 48
#define NSg 96
#define NBg 2
#define NVOX (NZg * NYg * NXg)          // 884736 voxels per batch
#define NRAY1 (NAg * NVg * NUg)         // 442368 rays per batch
#define PLANE (NYg * NXg)               // 9216 float2 elements per z-plane

typedef float v4f __attribute__((ext_vector_type(4)));  // default (16B) align

// ---------------- staging: both layouts + trig, one kernel ----------------
__global__ __launch_bounds__(256) void pack_b2_dual(
    const float* __restrict__ vol, float2* __restrict__ qx,
    float2* __restrict__ qy, float2* __restrict__ trig) {
    const int i = blockIdx.x * blockDim.x + threadIdx.x;  // [z][y][x]
    float2 p;
    p.x = vol[i];
    p.y = vol[i + NVOX];
    qx[i] = p;                                   // x-fast (coalesced)
    const int x = i % NXg;
    const int t = i / NXg;
    const int y = t % NYg;
    const int z = t / NYg;
    qy[(z * NXg + x) * NYg + y] = p;             // y-fast (scattered, cheap)
    if (i < NAg) {                               // 48-entry trig table
        const float dtheta = 6.2831855f / 48.0f; // f32(2*pi)/48, jax linspace
        const float theta  = (float)i * dtheta;
        float2 cs;
        cs.x = (float)cos((double)theta);
        cs.y = (float)sin((double)theta);
        trig[i] = cs;
    }
}

// ---------------- shared geometry (b-independent) -------------------------
__device__ __forceinline__ void ray_setup_cs(
    int ridx, float c, float s, float& srcx, float& srcy,
    float& dx, float& dy, float& dz, int& k0, int& k1) {
#pragma clang fp contract(off)
    const int u   = ridx % NUg;
    int tmp       = ridx / NUg;
    const int v   = tmp % NVg;

    srcx = 500.0f * c;
    srcy = 500.0f * s;
    const float uu = ((float)u - 47.5f) * 2.0f;
    const float vv = ((float)v - 47.5f) * 2.0f;
    const float pixx = (-500.0f * c) + uu * (-s);
    const float pixy = (-500.0f * s) + uu * c;
    const float pixz = vv;

    const float dx0 = pixx - srcx;
    const float dy0 = pixy - srcy;
    const float dz0 = pixz;
    const float nrm = sqrtf((dx0 * dx0 + dy0 * dy0) + dz0 * dz0);
    dx = dx0 / nrm;
    dy = dy0 / nrm;
    dz = dz0 / nrm;

    const float stepf = (float)1.7320508075688773;   // f32(2R/96)
    const float t0f   = (float)416.8615612366939;    // f32(DSO-R)

    // conservative AABB clip (skip-only; in-loop test is authoritative)
    const float LO = -47.51f, HI = 47.51f;
    float tlo = -1e30f, thi = 1e30f;
    {
        const float o3[3] = {srcx, srcy, 0.0f};
        const float d3[3] = {dx, dy, dz};
        bool empty = false;
        #pragma unroll
        for (int ax = 0; ax < 3; ++ax) {
            const float oo = o3[ax], dd = d3[ax];
            if (fabsf(dd) > 1e-8f) {
                const float inv = 1.0f / dd;
                const float ta = (LO - oo) * inv;
                const float tb = (HI - oo) * inv;
                tlo = fmaxf(tlo, fminf(ta, tb));
                thi = fminf(thi, fmaxf(ta, tb));
            } else if (oo < LO || oo > HI) {
                empty = true;
            }
        }
        if (empty) { tlo = 1.0f; thi = 0.0f; }
    }
    if (thi >= tlo) {
        k0 = (int)floorf((tlo - t0f) / stepf) - 2;
        k1 = (int)ceilf((thi - t0f) / stepf) + 2;
        k0 = max(k0, 0);
        k1 = min(k1, NSg - 1);
    } else {
        k0 = 1; k1 = 0;
    }
}

// ---------------- main: dual-layout gather, 1 thread per ray --------------
__global__ __launch_bounds__(256) void coneproj_b2dual(
    const float2* __restrict__ qx, const float2* __restrict__ qy,
    const float2* __restrict__ trig, float* __restrict__ out) {
#pragma clang fp contract(off)
    const int ridx = blockIdx.x * blockDim.x + threadIdx.x;  // (a*96+v)*96+u
    const int a    = ridx / (NUg * NVg);        // uniform per block (36 blk/angle)
    const float2 cs = trig[a];

    float srcx, srcy, dx, dy, dz;
    int k0, k1;
    ray_setup_cs(ridx, cs.x, cs.y, srcx, srcy, dx, dy, dz, k0, k1);

    const float stepf = (float)1.7320508075688773;
    const float t0f   = (float)416.8615612366939;

    // Layout select (uniform per block): u_ax = (-s, c, 0).
    // |s| >= |c|  => lanes walk x fastest => x-fast layout.
    // else        => lanes walk y fastest => y-fast layout.
    const bool xfast = fabsf(cs.y) >= fabsf(cs.x);
    const float2* __restrict__ q = xfast ? qx : qy;
    // (inner, mid) coordinate roles; expressions stay bit-identical to
    // the reference's ix / iy computations.
    const float src_i = xfast ? srcx : srcy;
    const float d_i   = xfast ? dx   : dy;
    const float src_m = xfast ? srcy : srcx;
    const float d_m   = xfast ? dy   : dx;

    float acc0 = 0.0f, acc1 = 0.0f;
    for (int k = k0; k <= k1; ++k) {
        const float tk = t0f + ((float)k + 0.5f) * stepf;
        const float ci = (src_i + d_i * tk) + 47.5f;   // inner coord (x or y)
        const float cm = (src_m + d_m * tk) + 47.5f;   // mid coord   (y or x)
        const float iz = (dz * tk) + 47.5f;
        if (ci >= 0.0f && ci <= 95.0f &&
            cm >= 0.0f && cm <= 95.0f &&
            iz >= 0.0f && iz <= 95.0f) {
            const int i0 = min((int)ci, 94);
            const int m0 = min((int)cm, 94);
            const int z0 = min((int)iz, NZg - 2);
            const float fi = ci - (float)i0;
            const float fm = cm - (float)m0;
            const float fz = iz - (float)z0;
            const int base = (z0 * 96 + m0) * 96 + i0;
            // 4 x 16B gathers: each row-load gives (b0@i0,b1@i0,b0@i1,b1@i1)
            // for one (mid, z) corner row of the selected layout.
            const v4f r00 = *(const v4f*)(q + base);                // (m0,z0)
            const v4f r01 = *(const v4f*)(q + base + 96);           // (m1,z0)
            const v4f r10 = *(const v4f*)(q + base + PLANE);        // (m0,z1)
            const v4f r11 = *(const v4f*)(q + base + PLANE + 96);   // (m1,z1)
            // batch 0: .x = b0@i0, .z = b0@i1
            {
                const float c00 = r00.x + fi * (r00.z - r00.x);
                const float c01 = r01.x + fi * (r01.z - r01.x);
                const float c10 = r10.x + fi * (r10.z - r10.x);
                const float c11 = r11.x + fi * (r11.z - r11.x);
                const float c0  = c00 + fm * (c01 - c00);
                const float c1  = c10 + fm * (c11 - c10);
                acc0 += c0 + fz * (c1 - c0);
            }
            // batch 1: .y = b1@i0, .w = b1@i1
            {
                const float c00 = r00.y + fi * (r00.w - r00.y);
                const float c01 = r01.y + fi * (r01.w - r01.y);
                const float c10 = r10.y + fi * (r10.w - r10.y);
                const float c11 = r11.y + fi * (r11.w - r11.y);
                const float c0  = c00 + fm * (c01 - c00);
                const float c1  = c10 + fm * (c11 - c10);
                acc1 += c0 + fz * (c1 - c0);
            }
        }
    }
    out[ridx]         = acc0 * stepf;
    out[ridx + NRAY1] = acc1 * stepf;
}

// ---------------- mid tier: R10 single-layout kernel ----------------------
__global__ __launch_bounds__(256) void pack_b2(
    const float* __restrict__ vol, float2* __restrict__ q) {
    const int i = blockIdx.x * blockDim.x + threadIdx.x;  // [z][y][x]
    float2 p;
    p.x = vol[i];
    p.y = vol[i + NVOX];
    q[i] = p;
}

__device__ __forceinline__ void ray_setup(
    int ridx, float& srcx, float& srcy, float& dx, float& dy, float& dz,
    int& k0, int& k1) {
#pragma clang fp contract(off)
    const int a = ridx / (NUg * NVg);
    const float dtheta = 6.2831855f / 48.0f;
    const float theta  = (float)a * dtheta;
    const float c = (float)cos((double)theta);
    const float s = (float)sin((double)theta);
    ray_setup_cs(ridx, c, s, srcx, srcy, dx, dy, dz, k0, k1);
}

__global__ __launch_bounds__(256) void coneproj_b2x4(
    const float2* __restrict__ q, float* __restrict__ out) {
#pragma clang fp contract(off)
    const int ridx = blockIdx.x * blockDim.x + threadIdx.x;
    float srcx, srcy, dx, dy, dz;
    int k0, k1;
    ray_setup(ridx, srcx, srcy, dx, dy, dz, k0, k1);

    const float stepf = (float)1.7320508075688773;
    const float t0f   = (float)416.8615612366939;

    float acc0 = 0.0f, acc1 = 0.0f;
    for (int k = k0; k <= k1; ++k) {
        const float tk = t0f + ((float)k + 0.5f) * stepf;
        const float ix = (srcx + dx * tk) + 47.5f;
        const float iy = (srcy + dy * tk) + 47.5f;
        const float iz = (dz * tk) + 47.5f;
        if (ix >= 0.0f && ix <= 95.0f &&
            iy >= 0.0f && iy <= 95.0f &&
            iz >= 0.0f && iz <= 95.0f) {
            const int x0 = min((int)ix, NXg - 2);
            const int y0 = min((int)iy, NYg - 2);
            const int z0 = min((int)iz, NZg - 2);
            const float fx = ix - (float)x0;
            const float fy = iy - (float)y0;
            const float fz = iz - (float)z0;
            const int base = (z0 * NYg + y0) * NXg + x0;
            const v4f r00 = *(const v4f*)(q + base);
            const v4f r01 = *(const v4f*)(q + base + NXg);
            const v4f r10 = *(const v4f*)(q + base + PLANE);
            const v4f r11 = *(const v4f*)(q + base + PLANE + NXg);
            {
                const float c00 = r00.x + fx * (r00.z - r00.x);
                const float c01 = r01.x + fx * (r01.z - r01.x);
                const float c10 = r10.x + fx * (r10.z - r10.x);
                const float c11 = r11.x + fx * (r11.z - r11.x);
                const float c0  = c00 + fy * (c01 - c00);
                const float c1  = c10 + fy * (c11 - c10);
                acc0 += c0 + fz * (c1 - c0);
            }
            {
                const float c00 = r00.y + fx * (r00.w - r00.y);
                const float c01 = r01.y + fx * (r01.w - r01.y);
                const float c10 = r10.y + fx * (r10.w - r10.y);
                const float c11 = r11.y + fx * (r11.w - r11.y);
                const float c0  = c00 + fy * (c01 - c00);
                const float c1  = c10 + fy * (c11 - c10);
                acc1 += c0 + fz * (c1 - c0);
            }
        }
    }
    out[ridx]         = acc0 * stepf;
    out[ridx + NRAY1] = acc1 * stepf;
}

// ---------------- fallback: direct 8-gather projector (R2) ----------------
__global__ __launch_bounds__(256) void coneproj_direct(
    const float* __restrict__ vol, float* __restrict__ out) {
#pragma clang fp contract(off)
    const int gidx = blockIdx.x * blockDim.x + threadIdx.x;  // includes b
    const int ridx = gidx % NRAY1;
    const int b    = gidx / NRAY1;
    float srcx, srcy, dx, dy, dz;
    int k0, k1;
    ray_setup(ridx, srcx, srcy, dx, dy, dz, k0, k1);

    const float stepf = (float)1.7320508075688773;
    const float t0f   = (float)416.8615612366939;

    const float* __restrict__ volb = vol + (size_t)b * NVOX;

    float acc = 0.0f;
    for (int k = k0; k <= k1; ++k) {
        const float tk = t0f + ((float)k + 0.5f) * stepf;
        const float ix = (srcx + dx * tk) + 47.5f;
        const float iy = (srcy + dy * tk) + 47.5f;
        const float iz = (dz * tk) + 47.5f;
        if (ix >= 0.0f && ix <= 95.0f &&
            iy >= 0.0f && iy <= 95.0f &&
            iz >= 0.0f && iz <= 95.0f) {
            const int x0 = min((int)ix, NXg - 2);
            const int y0 = min((int)iy, NYg - 2);
            const int z0 = min((int)iz, NZg - 2);
            const float fx = ix - (float)x0;
            const float fy = iy - (float)y0;
            const float fz = iz - (float)z0;
            const float* p = volb + ((z0 * NYg + y0) * NXg + x0);
            const float v000 = p[0];
            const float v001 = p[1];
            const float v010 = p[NXg];
            const float v011 = p[NXg + 1];
            const float v100 = p[NYg * NXg];
            const float v101 = p[NYg * NXg + 1];
            const float v110 = p[NYg * NXg + NXg];
            const float v111 = p[NYg * NXg + NXg + 1];
            const float c00 = v000 + fx * (v001 - v000);
            const float c01 = v010 + fx * (v011 - v010);
            const float c10 = v100 + fx * (v101 - v100);
            const float c11 = v110 + fx * (v111 - v110);
            const float c0  = c00 + fy * (c01 - c00);
            const float c1  = c10 + fy * (c11 - c10);
            acc += c0 + fz * (c1 - c0);
        }
    }
    out[gidx] = acc * stepf;
}

extern "C" void kernel_launch(void* const* d_in, const int* in_sizes, int n_in,
                              void* d_out, int out_size, void* d_ws, size_t ws_size,
                              hipStream_t stream) {
    const float* vol = (const float*)d_in[0];
    float* out = (float*)d_out;
    const size_t need_dual   = 2 * (size_t)NVOX * sizeof(float2)
                             + (size_t)NAg * sizeof(float2);   // ~14.2 MB
    const size_t need_single = (size_t)NVOX * sizeof(float2);  // ~7.08 MB
    if (ws_size >= need_dual) {
        float2* qx   = (float2*)d_ws;
        float2* qy   = qx + NVOX;
        float2* trig = qy + NVOX;
        pack_b2_dual<<<NVOX / 256, 256, 0, stream>>>(vol, qx, qy, trig);
        coneproj_b2dual<<<NRAY1 / 256, 256, 0, stream>>>(qx, qy, trig, out);
    } else if (ws_size >= need_single) {
        float2* q = (float2*)d_ws;
        pack_b2<<<NVOX / 256, 256, 0, stream>>>(vol, q);
        coneproj_b2x4<<<NRAY1 / 256, 256, 0, stream>>>(q, out);
    } else {
        coneproj_direct<<<(NBg * NRAY1) / 256, 256, 0, stream>>>(vol, out);
    }
}

// Round 4
// 190.288 us; speedup vs baseline: 1.2602x; 1.0311x over previous
//
#include <hip/hip_runtime.h>
#include <math.h>

// Cone-beam forward projection (TIGRE Ax analogue).
// Volume: [B=2, NZ=96, NY=96, NX=96] f32, ZYX layout (x fastest).
// Output: [B=2, A=48, NV=96, NU=96] f32.
//
// R14 = R13 (dual per-angle layout: x-fast [z][y][x] + y-fast [z][x][y],
// batch-interleaved float2, 4x dwordx4 gathers) + 2-threads-per-ray
// contiguous-half chunking with LDS pair-reduce.
// Evidence: R13 counters show TA ~45%, VALU 31%, occ 49% -- nothing
// saturated => latency/drain-bound. R12 proved chunking raises occupancy;
// it failed only on the single layout (TA-saturated). Wave mapping keeps
// 64 lanes = 64 consecutive u of one chunk -> per-instruction line
// footprint unchanged. Pack's y-fast scatter replaced by LDS-tiled
// transpose (was 768B-stride scatter).
//
// CORRECTNESS-CRITICAL: reference integrand is DISCONTINUOUS at cube faces.
// Position path replicates the reference's f32 op sequence exactly:
// contract(off), per-sample src + d*t, IEEE sqrt+div, f64-rounded trig.
// Chunk seam only reassociates the +acc sum (one seam; R12 passed with 3).

#define NZg 96
#define NYg 96
#define NXg 96
#define NVg 96
#define NUg 96
#define NAg 48
#define NSg 96
#define NBg 2
#define NVOX (NZg * NYg * NXg)          // 884736 voxels per batch
#define NRAY1 (NAg * NVg * NUg)         // 442368 rays per batch
#define PLANE (NYg * NXg)               // 9216 float2 elements per z-plane

typedef float v4f __attribute__((ext_vector_type(4)));  // default (16B) align

// ---------------- staging: x-fast copy + LDS-tiled y-fast transpose -------
__global__ __launch_bounds__(256) void pack_b2_dual_t(
    const float* __restrict__ vol, float2* __restrict__ qx,
    float2* __restrict__ qy) {
    __shared__ float2 tile[16][17];             // +1 pad: no bank conflicts
    const int z      = blockIdx.x / 36;
    const int tileId = blockIdx.x % 36;
    const int y0 = (tileId / 6) * 16;
    const int x0 = (tileId % 6) * 16;
    const int tx = threadIdx.x & 15;
    const int ty = threadIdx.x >> 4;
    const int idx = (z * NYg + (y0 + ty)) * NXg + (x0 + tx);
    float2 p;
    p.x = vol[idx];
    p.y = vol[idx + NVOX];
    qx[idx] = p;                                 // x-fast (coalesced)
    tile[ty][tx] = p;
    __syncthreads();
    // transposed write: consecutive tx -> consecutive y (coalesced)
    qy[(z * NXg + (x0 + ty)) * NYg + (y0 + tx)] = tile[tx][ty];
}

// ---------------- per-angle trig table (bit-identical to inline calc) -----
__global__ void make_trig(float2* __restrict__ trig) {
    const int a = threadIdx.x;
    if (a < NAg) {
        const float dtheta = 6.2831855f / 48.0f; // f32(2*pi)/48, jax linspace
        const float theta  = (float)a * dtheta;
        float2 cs;
        cs.x = (float)cos((double)theta);
        cs.y = (float)sin((double)theta);
        trig[a] = cs;
    }
}

// ---------------- shared geometry (b-independent) -------------------------
__device__ __forceinline__ void ray_setup_cs(
    int ridx, float c, float s, float& srcx, float& srcy,
    float& dx, float& dy, float& dz, int& k0, int& k1) {
#pragma clang fp contract(off)
    const int u   = ridx % NUg;
    int tmp       = ridx / NUg;
    const int v   = tmp % NVg;

    srcx = 500.0f * c;
    srcy = 500.0f * s;
    const float uu = ((float)u - 47.5f) * 2.0f;
    const float vv = ((float)v - 47.5f) * 2.0f;
    const float pixx = (-500.0f * c) + uu * (-s);
    const float pixy = (-500.0f * s) + uu * c;
    const float pixz = vv;

    const float dx0 = pixx - srcx;
    const float dy0 = pixy - srcy;
    const float dz0 = pixz;
    const float nrm = sqrtf((dx0 * dx0 + dy0 * dy0) + dz0 * dz0);
    dx = dx0 / nrm;
    dy = dy0 / nrm;
    dz = dz0 / nrm;

    const float stepf = (float)1.7320508075688773;   // f32(2R/96)
    const float t0f   = (float)416.8615612366939;    // f32(DSO-R)

    // conservative AABB clip (skip-only; in-loop test is authoritative)
    const float LO = -47.51f, HI = 47.51f;
    float tlo = -1e30f, thi = 1e30f;
    {
        const float o3[3] = {srcx, srcy, 0.0f};
        const float d3[3] = {dx, dy, dz};
        bool empty = false;
        #pragma unroll
        for (int ax = 0; ax < 3; ++ax) {
            const float oo = o3[ax], dd = d3[ax];
            if (fabsf(dd) > 1e-8f) {
                const float inv = 1.0f / dd;
                const float ta = (LO - oo) * inv;
                const float tb = (HI - oo) * inv;
                tlo = fmaxf(tlo, fminf(ta, tb));
                thi = fminf(thi, fmaxf(ta, tb));
            } else if (oo < LO || oo > HI) {
                empty = true;
            }
        }
        if (empty) { tlo = 1.0f; thi = 0.0f; }
    }
    if (thi >= tlo) {
        k0 = (int)floorf((tlo - t0f) / stepf) - 2;
        k1 = (int)ceilf((thi - t0f) / stepf) + 2;
        k0 = max(k0, 0);
        k1 = min(k1, NSg - 1);
    } else {
        k0 = 1; k1 = 0;
    }
}

// ---------------- main: dual layout, 2 threads/ray, LDS pair-reduce -------
// Block: 256 threads = 128 rays x 2 chunks.
//   wave 0: chunk0, rays   0..63   wave 1: chunk0, rays  64..127
//   wave 2: chunk1, rays   0..63   wave 3: chunk1, rays  64..127
// => every wave's 64 lanes are 64 consecutive rays (line clustering kept).
__global__ __launch_bounds__(256) void coneproj_b2dual_c2(
    const float2* __restrict__ qx, const float2* __restrict__ qy,
    const float2* __restrict__ trig, float* __restrict__ out) {
#pragma clang fp contract(off)
    const int lane     = threadIdx.x & 63;
    const int wid      = threadIdx.x >> 6;
    const int chunk    = wid >> 1;                    // 0 or 1
    const int rayInBlk = ((wid & 1) << 6) + lane;     // 0..127
    const int ridx = blockIdx.x * 128 + rayInBlk;     // (a*96+v)*96+u
    const int a    = ridx / (NUg * NVg);              // uniform per block
    const float2 cs = trig[a];

    float srcx, srcy, dx, dy, dz;
    int k0, k1;
    ray_setup_cs(ridx, cs.x, cs.y, srcx, srcy, dx, dy, dz, k0, k1);

    const float stepf = (float)1.7320508075688773;
    const float t0f   = (float)416.8615612366939;

    // Layout select (uniform per block): u_ax = (-s, c, 0).
    const bool xfast = fabsf(cs.y) >= fabsf(cs.x);
    const float2* __restrict__ q = xfast ? qx : qy;
    const float src_i = xfast ? srcx : srcy;
    const float d_i   = xfast ? dx   : dy;
    const float src_m = xfast ? srcy : srcx;
    const float d_m   = xfast ? dy   : dx;

    // contiguous half of [k0, k1]
    const int len = (k1 - k0 + 2) >> 1;               // ceil(n/2)
    const int kb0 = k0 + chunk * len;
    const int kb1 = min(kb0 + len - 1, k1);

    float acc0 = 0.0f, acc1 = 0.0f;
    for (int k = kb0; k <= kb1; ++k) {
        const float tk = t0f + ((float)k + 0.5f) * stepf;
        const float ci = (src_i + d_i * tk) + 47.5f;   // inner coord (x or y)
        const float cm = (src_m + d_m * tk) + 47.5f;   // mid coord   (y or x)
        const float iz = (dz * tk) + 47.5f;
        if (ci >= 0.0f && ci <= 95.0f &&
            cm >= 0.0f && cm <= 95.0f &&
            iz >= 0.0f && iz <= 95.0f) {
            const int i0 = min((int)ci, 94);
            const int m0 = min((int)cm, 94);
            const int z0 = min((int)iz, NZg - 2);
            const float fi = ci - (float)i0;
            const float fm = cm - (float)m0;
            const float fz = iz - (float)z0;
            const int base = (z0 * 96 + m0) * 96 + i0;
            // 4 x 16B gathers: each row-load gives (b0@i0,b1@i0,b0@i1,b1@i1)
            const v4f r00 = *(const v4f*)(q + base);                // (m0,z0)
            const v4f r01 = *(const v4f*)(q + base + 96);           // (m1,z0)
            const v4f r10 = *(const v4f*)(q + base + PLANE);        // (m0,z1)
            const v4f r11 = *(const v4f*)(q + base + PLANE + 96);   // (m1,z1)
            // batch 0: .x = b0@i0, .z = b0@i1
            {
                const float c00 = r00.x + fi * (r00.z - r00.x);
                const float c01 = r01.x + fi * (r01.z - r01.x);
                const float c10 = r10.x + fi * (r10.z - r10.x);
                const float c11 = r11.x + fi * (r11.z - r11.x);
                const float c0  = c00 + fm * (c01 - c00);
                const float c1  = c10 + fm * (c11 - c10);
                acc0 += c0 + fz * (c1 - c0);
            }
            // batch 1: .y = b1@i0, .w = b1@i1
            {
                const float c00 = r00.y + fi * (r00.w - r00.y);
                const float c01 = r01.y + fi * (r01.w - r01.y);
                const float c10 = r10.y + fi * (r10.w - r10.y);
                const float c11 = r11.y + fi * (r11.w - r11.y);
                const float c0  = c00 + fm * (c01 - c00);
                const float c1  = c10 + fm * (c11 - c10);
                acc1 += c0 + fz * (c1 - c0);
            }
        }
    }

    // ---- combine the 2 chunks (fixed order: c0 + c1) ----
    __shared__ float p0[256];
    __shared__ float p1[256];
    p0[chunk * 128 + rayInBlk] = acc0;
    p1[chunk * 128 + rayInBlk] = acc1;
    __syncthreads();
    if (threadIdx.x < 128) {
        const int r = blockIdx.x * 128 + threadIdx.x;
        const float s0 = p0[threadIdx.x] + p0[threadIdx.x + 128];
        const float s1 = p1[threadIdx.x] + p1[threadIdx.x + 128];
        out[r]         = s0 * stepf;
        out[r + NRAY1] = s1 * stepf;
    }
}

// ---------------- mid tier: R10 single-layout kernel ----------------------
__global__ __launch_bounds__(256) void pack_b2(
    const float* __restrict__ vol, float2* __restrict__ q) {
    const int i = blockIdx.x * blockDim.x + threadIdx.x;  // [z][y][x]
    float2 p;
    p.x = vol[i];
    p.y = vol[i + NVOX];
    q[i] = p;
}

__device__ __forceinline__ void ray_setup(
    int ridx, float& srcx, float& srcy, float& dx, float& dy, float& dz,
    int& k0, int& k1) {
#pragma clang fp contract(off)
    const int a = ridx / (NUg * NVg);
    const float dtheta = 6.2831855f / 48.0f;
    const float theta  = (float)a * dtheta;
    const float c = (float)cos((double)theta);
    const float s = (float)sin((double)theta);
    ray_setup_cs(ridx, c, s, srcx, srcy, dx, dy, dz, k0, k1);
}

__global__ __launch_bounds__(256) void coneproj_b2x4(
    const float2* __restrict__ q, float* __restrict__ out) {
#pragma clang fp contract(off)
    const int ridx = blockIdx.x * blockDim.x + threadIdx.x;
    float srcx, srcy, dx, dy, dz;
    int k0, k1;
    ray_setup(ridx, srcx, srcy, dx, dy, dz, k0, k1);

    const float stepf = (float)1.7320508075688773;
    const float t0f   = (float)416.8615612366939;

    float acc0 = 0.0f, acc1 = 0.0f;
    for (int k = k0; k <= k1; ++k) {
        const float tk = t0f + ((float)k + 0.5f) * stepf;
        const float ix = (srcx + dx * tk) + 47.5f;
        const float iy = (srcy + dy * tk) + 47.5f;
        const float iz = (dz * tk) + 47.5f;
        if (ix >= 0.0f && ix <= 95.0f &&
            iy >= 0.0f && iy <= 95.0f &&
            iz >= 0.0f && iz <= 95.0f) {
            const int x0 = min((int)ix, NXg - 2);
            const int y0 = min((int)iy, NYg - 2);
            const int z0 = min((int)iz, NZg - 2);
            const float fx = ix - (float)x0;
            const float fy = iy - (float)y0;
            const float fz = iz - (float)z0;
            const int base = (z0 * NYg + y0) * NXg + x0;
            const v4f r00 = *(const v4f*)(q + base);
            const v4f r01 = *(const v4f*)(q + base + NXg);
            const v4f r10 = *(const v4f*)(q + base + PLANE);
            const v4f r11 = *(const v4f*)(q + base + PLANE + NXg);
            {
                const float c00 = r00.x + fx * (r00.z - r00.x);
                const float c01 = r01.x + fx * (r01.z - r01.x);
                const float c10 = r10.x + fx * (r10.z - r10.x);
                const float c11 = r11.x + fx * (r11.z - r11.x);
                const float c0  = c00 + fy * (c01 - c00);
                const float c1  = c10 + fy * (c11 - c10);
                acc0 += c0 + fz * (c1 - c0);
            }
            {
                const float c00 = r00.y + fx * (r00.w - r00.y);
                const float c01 = r01.y + fx * (r01.w - r01.y);
                const float c10 = r10.y + fx * (r10.w - r10.y);
                const float c11 = r11.y + fx * (r11.w - r11.y);
                const float c0  = c00 + fy * (c01 - c00);
                const float c1  = c10 + fy * (c11 - c10);
                acc1 += c0 + fz * (c1 - c0);
            }
        }
    }
    out[ridx]         = acc0 * stepf;
    out[ridx + NRAY1] = acc1 * stepf;
}

// ---------------- fallback: direct 8-gather projector (R2) ----------------
__global__ __launch_bounds__(256) void coneproj_direct(
    const float* __restrict__ vol, float* __restrict__ out) {
#pragma clang fp contract(off)
    const int gidx = blockIdx.x * blockDim.x + threadIdx.x;  // includes b
    const int ridx = gidx % NRAY1;
    const int b    = gidx / NRAY1;
    float srcx, srcy, dx, dy, dz;
    int k0, k1;
    ray_setup(ridx, srcx, srcy, dx, dy, dz, k0, k1);

    const float stepf = (float)1.7320508075688773;
    const float t0f   = (float)416.8615612366939;

    const float* __restrict__ volb = vol + (size_t)b * NVOX;

    float acc = 0.0f;
    for (int k = k0; k <= k1; ++k) {
        const float tk = t0f + ((float)k + 0.5f) * stepf;
        const float ix = (srcx + dx * tk) + 47.5f;
        const float iy = (srcy + dy * tk) + 47.5f;
        const float iz = (dz * tk) + 47.5f;
        if (ix >= 0.0f && ix <= 95.0f &&
            iy >= 0.0f && iy <= 95.0f &&
            iz >= 0.0f && iz <= 95.0f) {
            const int x0 = min((int)ix, NXg - 2);
            const int y0 = min((int)iy, NYg - 2);
            const int z0 = min((int)iz, NZg - 2);
            const float fx = ix - (float)x0;
            const float fy = iy - (float)y0;
            const float fz = iz - (float)z0;
            const float* p = volb + ((z0 * NYg + y0) * NXg + x0);
            const float v000 = p[0];
            const float v001 = p[1];
            const float v010 = p[NXg];
            const float v011 = p[NXg + 1];
            const float v100 = p[NYg * NXg];
            const float v101 = p[NYg * NXg + 1];
            const float v110 = p[NYg * NXg + NXg];
            const float v111 = p[NYg * NXg + NXg + 1];
            const float c00 = v000 + fx * (v001 - v000);
            const float c01 = v010 + fx * (v011 - v010);
            const float c10 = v100 + fx * (v101 - v100);
            const float c11 = v110 + fx * (v111 - v110);
            const float c0  = c00 + fy * (c01 - c00);
            const float c1  = c10 + fy * (c11 - c10);
            acc += c0 + fz * (c1 - c0);
        }
    }
    out[gidx] = acc * stepf;
}

extern "C" void kernel_launch(void* const* d_in, const int* in_sizes, int n_in,
                              void* d_out, int out_size, void* d_ws, size_t ws_size,
                              hipStream_t stream) {
    const float* vol = (const float*)d_in[0];
    float* out = (float*)d_out;
    const size_t need_dual   = 2 * (size_t)NVOX * sizeof(float2)
                             + (size_t)NAg * sizeof(float2);   // ~14.2 MB
    const size_t need_single = (size_t)NVOX * sizeof(float2);  // ~7.08 MB
    if (ws_size >= need_dual) {
        float2* qx   = (float2*)d_ws;
        float2* qy   = qx + NVOX;
        float2* trig = qy + NVOX;
        pack_b2_dual_t<<<96 * 36, 256, 0, stream>>>(vol, qx, qy);
        make_trig<<<1, 64, 0, stream>>>(trig);
        coneproj_b2dual_c2<<<NRAY1 / 128, 256, 0, stream>>>(qx, qy, trig, out);
    } else if (ws_size >= need_single) {
        float2* q = (float2*)d_ws;
        pack_b2<<<NVOX / 256, 256, 0, stream>>>(vol, q);
        coneproj_b2x4<<<NRAY1 / 256, 256, 0, stream>>>(q, out);
    } else {
        coneproj_direct<<<(NBg * NRAY1) / 256, 256, 0, stream>>>(vol, out);
    }
}